// Round 1
// baseline (13502.188 us; speedup 1.0000x reference)
//
#include <hip/hip_runtime.h>
#include <math.h>

#define BATCH 512
#define SEQ   200
#define DIN   64
#define HID   512
#define GW    2048   // 4*HID
#define EPS   1e-5f

__device__ __forceinline__ float sigf(float x){ return 1.0f/(1.0f+expf(-x)); }

// Reduce 4 values across a 256-thread block. red must be float[16] shared.
__device__ __forceinline__ void block_reduce4(float&a,float&b,float&c,float&d,float* red){
  #pragma unroll
  for(int o=32;o;o>>=1){
    a+=__shfl_down(a,o); b+=__shfl_down(b,o);
    c+=__shfl_down(c,o); d+=__shfl_down(d,o);
  }
  const int lane = threadIdx.x & 63, wid = threadIdx.x>>6;
  if(lane==0){ red[wid*4+0]=a; red[wid*4+1]=b; red[wid*4+2]=c; red[wid*4+3]=d; }
  __syncthreads();
  a = red[0]+red[4]+red[8]+red[12];
  b = red[1]+red[5]+red[9]+red[13];
  c = red[2]+red[6]+red[10]+red[14];
  d = red[3]+red[7]+red[11]+red[15];
  __syncthreads();
}

// Per-batch-row stats for ln1 (joint LayerNorm over (S,D) = 12800 elems)
__global__ __launch_bounds__(256) void ln1_stats(const float* __restrict__ x,
                                                 float* __restrict__ mu,
                                                 float* __restrict__ rs){
  const int b = blockIdx.x;
  const float* xb = x + (size_t)b*SEQ*DIN;
  float s=0, ss=0, d=0, e=0;
  for (int i=threadIdx.x; i<SEQ*DIN; i+=256){ float v=xb[i]; s+=v; ss+=v*v; }
  __shared__ float red[16];
  block_reduce4(s,ss,d,e,red);
  if (threadIdx.x==0){
    float m = s*(1.0f/(SEQ*DIN));
    mu[b] = m;
    rs[b] = rsqrtf(ss*(1.0f/(SEQ*DIN)) - m*m + EPS);
  }
}

// One tick: computes the 4 gate pre-activation matrices (+bias), layer-1 skewed.
//  which 0: G_ih0 = ln1(x[:,t,:]) @ W_ih0^T + b_ih0     (K=64)   [valid t<200]
//  which 1: G_hh0 = h0 @ W_hh0^T + b_hh0                (K=512)  [valid t<200]
//  which 2: G_ih1 = h0 @ W_ih1^T + b_ih1                (K=512)  [valid t>=1]
//  which 3: G_hh1 = h1 @ W_hh1^T + b_hh1                (K=512)  [valid t>=1]
// grid = (128, 8): blockIdx.x -> which(2b) x n-tile(32), blockIdx.y -> m-tile(8)
__global__ __launch_bounds__(256) void tick_matmul(
    const float* __restrict__ x, const float* __restrict__ g1, const float* __restrict__ b1,
    const float* __restrict__ W_ih0, const float* __restrict__ b_ih0,
    const float* __restrict__ W_hh0, const float* __restrict__ b_hh0,
    const float* __restrict__ W_ih1, const float* __restrict__ b_ih1,
    const float* __restrict__ W_hh1, const float* __restrict__ b_hh1,
    const float* __restrict__ mu, const float* __restrict__ rsg,
    const float* __restrict__ h0, const float* __restrict__ h1,
    float* __restrict__ G, int t)
{
  __shared__ float As[16][68];   // [k][m], +4 pad keeps float4 alignment, no pow2 stride
  __shared__ float Bs[16][68];   // [k][n]
  const int which = blockIdx.x >> 5;
  const int n0 = (blockIdx.x & 31) * 64;
  const int m0 = blockIdx.y * 64;

  const float* A   = h0;
  const float* Bp  = W_hh0;
  const float* bias= b_hh0;
  int Kdim = HID;
  if      (which==0){ Bp=W_ih0; bias=b_ih0; Kdim=DIN; }
  else if (which==2){ Bp=W_ih1; bias=b_ih1; }
  else if (which==3){ A=h1; Bp=W_hh1; bias=b_hh1; }

  const int tq = (t < SEQ) ? t : (SEQ-1);   // t==200 layer0 result unused
  const int tid  = threadIdx.x;
  const int lrow = tid >> 2;        // 0..63 : row (m or n) loaded by this thread
  const int lk   = (tid & 3) * 4;   // 0,4,8,12 : k offset
  const int tx   = tid & 15, ty = tid >> 4;

  float acc[4][4] = {};

  for (int k0 = 0; k0 < Kdim; k0 += 16) {
    float av[4];
    if (which == 0) {
      const int br = m0 + lrow;            // batch row
      const int k  = k0 + lk;
      const float m = mu[br], r = rsg[br];
      #pragma unroll
      for (int j=0;j<4;j++){
        float xv = x[(size_t)br*(SEQ*DIN) + tq*DIN + k + j];
        av[j] = (xv - m)*r*g1[tq*DIN+k+j] + b1[tq*DIN+k+j];
      }
    } else {
      const float4 v = *(const float4*)(A + (size_t)(m0+lrow)*HID + k0 + lk);
      av[0]=v.x; av[1]=v.y; av[2]=v.z; av[3]=v.w;
    }
    const float4 bvv = *(const float4*)(Bp + (size_t)(n0+lrow)*Kdim + k0 + lk);
    const float bv[4] = {bvv.x,bvv.y,bvv.z,bvv.w};

    __syncthreads();
    #pragma unroll
    for (int j=0;j<4;j++){ As[lk+j][lrow]=av[j]; Bs[lk+j][lrow]=bv[j]; }
    __syncthreads();

    #pragma unroll
    for (int kk=0;kk<16;kk++){
      const float4 a4 = *(const float4*)&As[kk][ty*4];
      const float4 b4 = *(const float4*)&Bs[kk][tx*4];
      const float aa[4]={a4.x,a4.y,a4.z,a4.w};
      const float bb[4]={b4.x,b4.y,b4.z,b4.w};
      #pragma unroll
      for(int i=0;i<4;i++)
        #pragma unroll
        for(int j=0;j<4;j++)
          acc[i][j] += aa[i]*bb[j];
    }
  }

  float* Gout = G + (size_t)which*BATCH*GW;
  const float bn[4] = {bias[n0+tx*4+0],bias[n0+tx*4+1],bias[n0+tx*4+2],bias[n0+tx*4+3]};
  #pragma unroll
  for (int i=0;i<4;i++){
    float4 o4 = make_float4(acc[i][0]+bn[0], acc[i][1]+bn[1],
                            acc[i][2]+bn[2], acc[i][3]+bn[3]);
    *(float4*)(Gout + (size_t)(m0+ty*4+i)*GW + n0 + tx*4) = o4;
  }
}

// One block per (layer, batch-row): gate LN + cell update + h LN.
__global__ __launch_bounds__(256) void tick_update(
    const float* __restrict__ G,
    const float* __restrict__ g_ih0, const float* __restrict__ be_ih0,
    const float* __restrict__ g_hh0, const float* __restrict__ be_hh0,
    const float* __restrict__ g_ho0, const float* __restrict__ be_ho0,
    const float* __restrict__ g_ih1, const float* __restrict__ be_ih1,
    const float* __restrict__ g_hh1, const float* __restrict__ be_hh1,
    const float* __restrict__ g_ho1, const float* __restrict__ be_ho1,
    float* __restrict__ h0, float* __restrict__ c0,
    float* __restrict__ h1, float* __restrict__ c1, int t)
{
  const int layer = blockIdx.x >> 9;
  const int b = blockIdx.x & 511;
  if (layer==0 && t>=SEQ) return;   // layer0 active ticks 0..199
  if (layer==1 && t==0)   return;   // layer1 active ticks 1..200 (processes step t-1)

  const float *Ga,*Gb,*gA,*bA,*gB,*bB,*gH,*bH; float *cs,*hs;
  if (layer==0){
    Ga = G + (size_t)b*GW;
    Gb = G + (size_t)BATCH*GW + (size_t)b*GW;
    gA=g_ih0; bA=be_ih0; gB=g_hh0; bB=be_hh0; gH=g_ho0; bH=be_ho0;
    cs = c0 + b*HID; hs = h0 + b*HID;
  } else {
    Ga = G + 2*(size_t)BATCH*GW + (size_t)b*GW;
    Gb = G + 3*(size_t)BATCH*GW + (size_t)b*GW;
    gA=g_ih1; bA=be_ih1; gB=g_hh1; bB=be_hh1; gH=g_ho1; bH=be_ho1;
    cs = c1 + b*HID; hs = h1 + b*HID;
  }

  const int tid = threadIdx.x;
  __shared__ float red[16];
  __shared__ float su[HID];
  __shared__ float so[HID];

  // Pass 1: LN stats for both gate pre-activation vectors (2048 each)
  float sa=0, ssa=0, sb=0, ssb=0;
  for (int i=tid;i<GW;i+=256){
    float va=Ga[i]; sa+=va; ssa+=va*va;
    float vb=Gb[i]; sb+=vb; ssb+=vb*vb;
  }
  block_reduce4(sa,ssa,sb,ssb,red);
  const float ma = sa*(1.0f/GW);
  const float ra = rsqrtf(ssa*(1.0f/GW) - ma*ma + EPS);
  const float mb = sb*(1.0f/GW);
  const float rb = rsqrtf(ssb*(1.0f/GW) - mb*mb + EPS);

  // Pass 2: gates (i,f,g,o split), cell update, tanh(c) stats
  float s_u=0, s_uu=0;
  for (int j=tid;j<HID;j+=256){
    float iv = ((Ga[j      ]-ma)*ra*gA[j      ]+bA[j      ]) + ((Gb[j      ]-mb)*rb*gB[j      ]+bB[j      ]);
    float fv = ((Ga[j+  HID]-ma)*ra*gA[j+  HID]+bA[j+  HID]) + ((Gb[j+  HID]-mb)*rb*gB[j+  HID]+bB[j+  HID]);
    float gv = ((Ga[j+2*HID]-ma)*ra*gA[j+2*HID]+bA[j+2*HID]) + ((Gb[j+2*HID]-mb)*rb*gB[j+2*HID]+bB[j+2*HID]);
    float ov = ((Ga[j+3*HID]-ma)*ra*gA[j+3*HID]+bA[j+3*HID]) + ((Gb[j+3*HID]-mb)*rb*gB[j+3*HID]+bB[j+3*HID]);
    float cn = sigf(fv)*cs[j] + sigf(iv)*tanhf(gv);
    cs[j] = cn;
    float u = tanhf(cn);
    su[j] = u; so[j] = sigf(ov);
    s_u += u; s_uu += u*u;
  }
  float d3=0,d4=0;
  block_reduce4(s_u,s_uu,d3,d4,red);
  const float mu_u = s_u*(1.0f/HID);
  const float ru   = rsqrtf(s_uu*(1.0f/HID) - mu_u*mu_u + EPS);

  // Pass 3: h = sigmoid(o) * LN(tanh(c))
  for (int j=tid;j<HID;j+=256){
    hs[j] = so[j] * ((su[j]-mu_u)*ru*gH[j] + bH[j]);
  }
}

// Dense head: 512 -> 128 -> 64 -> 32 -> 1, one block per batch row
__global__ __launch_bounds__(256) void head_kernel(
    const float* __restrict__ h1,
    const float* __restrict__ Wd1, const float* __restrict__ bd1,
    const float* __restrict__ Wd2, const float* __restrict__ bd2,
    const float* __restrict__ Wd3, const float* __restrict__ bd3,
    const float* __restrict__ Wd4, const float* __restrict__ bd4,
    float* __restrict__ out)
{
  const int b = blockIdx.x;
  __shared__ float hv[HID];
  __shared__ float z1[128];
  __shared__ float z2[64];
  __shared__ float z3[32];
  const int tid = threadIdx.x;
  for (int i=tid;i<HID;i+=256) hv[i]=h1[(size_t)b*HID+i];
  __syncthreads();
  if (tid<128){
    float acc=bd1[tid]; const float* w=Wd1+(size_t)tid*512;
    for(int k=0;k<512;k++) acc+=hv[k]*w[k];
    z1[tid]=fmaxf(acc,0.f);
  }
  __syncthreads();
  if (tid<64){
    float acc=bd2[tid]; const float* w=Wd2+(size_t)tid*128;
    for(int k=0;k<128;k++) acc+=z1[k]*w[k];
    z2[tid]=fmaxf(acc,0.f);
  }
  __syncthreads();
  if (tid<32){
    float acc=bd3[tid]; const float* w=Wd3+(size_t)tid*64;
    for(int k=0;k<64;k++) acc+=z2[k]*w[k];
    z3[tid]=fmaxf(acc,0.f);
  }
  __syncthreads();
  if (tid==0){
    float acc=bd4[0];
    for(int k=0;k<32;k++) acc+=z3[k]*Wd4[k];
    out[b]=acc;
  }
}

extern "C" void kernel_launch(void* const* d_in, const int* in_sizes, int n_in,
                              void* d_out, int out_size, void* d_ws, size_t ws_size,
                              hipStream_t stream) {
  const float* x      = (const float*)d_in[0];
  const float* ln1_g  = (const float*)d_in[1];
  const float* ln1_b  = (const float*)d_in[2];
  const float* W_ih0  = (const float*)d_in[3];
  const float* b_ih0  = (const float*)d_in[4];
  const float* W_hh0  = (const float*)d_in[5];
  const float* b_hh0  = (const float*)d_in[6];
  const float* g_ih0  = (const float*)d_in[7];
  const float* be_ih0 = (const float*)d_in[8];
  const float* g_hh0  = (const float*)d_in[9];
  const float* be_hh0 = (const float*)d_in[10];
  const float* g_ho0  = (const float*)d_in[11];
  const float* be_ho0 = (const float*)d_in[12];
  const float* W_ih1  = (const float*)d_in[13];
  const float* b_ih1  = (const float*)d_in[14];
  const float* W_hh1  = (const float*)d_in[15];
  const float* b_hh1  = (const float*)d_in[16];
  const float* g_ih1  = (const float*)d_in[17];
  const float* be_ih1 = (const float*)d_in[18];
  const float* g_hh1  = (const float*)d_in[19];
  const float* be_hh1 = (const float*)d_in[20];
  const float* g_ho1  = (const float*)d_in[21];
  const float* be_ho1 = (const float*)d_in[22];
  const float* Wd1    = (const float*)d_in[23];
  const float* bd1    = (const float*)d_in[24];
  const float* Wd2    = (const float*)d_in[25];
  const float* bd2    = (const float*)d_in[26];
  const float* Wd3    = (const float*)d_in[27];
  const float* bd3    = (const float*)d_in[28];
  const float* Wd4    = (const float*)d_in[29];
  const float* bd4    = (const float*)d_in[30];
  float* out = (float*)d_out;

  float* ws = (float*)d_ws;
  float* G  = ws;                                   // 4 * 512*2048 = 4,194,304 floats
  float* h0 = ws + 4*(size_t)BATCH*GW;              // states: 4 * 512*512, contiguous
  float* c0 = h0 + (size_t)BATCH*HID;
  float* h1 = c0 + (size_t)BATCH*HID;
  float* c1 = h1 + (size_t)BATCH*HID;
  float* mu = c1 + (size_t)BATCH*HID;               // 512
  float* rs = mu + BATCH;                           // 512

  // zero the recurrent state (ws is re-poisoned before every launch)
  hipMemsetAsync(h0, 0, 4*(size_t)BATCH*HID*sizeof(float), stream);
  ln1_stats<<<BATCH, 256, 0, stream>>>(x, mu, rs);

  dim3 mgrid(128, 8);
  for (int t = 0; t <= SEQ; ++t) {
    tick_matmul<<<mgrid, 256, 0, stream>>>(x, ln1_g, ln1_b,
        W_ih0, b_ih0, W_hh0, b_hh0, W_ih1, b_ih1, W_hh1, b_hh1,
        mu, rs, h0, h1, G, t);
    tick_update<<<dim3(1024), 256, 0, stream>>>(G,
        g_ih0, be_ih0, g_hh0, be_hh0, g_ho0, be_ho0,
        g_ih1, be_ih1, g_hh1, be_hh1, g_ho1, be_ho1,
        h0, c0, h1, c1, t);
  }
  head_kernel<<<BATCH, 256, 0, stream>>>(h1, Wd1, bd1, Wd2, bd2, Wd3, bd3, Wd4, bd4, out);
}

// Round 2
// 11656.100 us; speedup vs baseline: 1.1584x; 1.1584x over previous
//
#include <hip/hip_runtime.h>
#include <math.h>

#define BATCH 512
#define SEQ   200
#define DIN   64
#define HID   512
#define GW    2048   // 4*HID
#define EPS   1e-5f

typedef _Float16 half_t;
typedef half_t half8 __attribute__((ext_vector_type(8)));
typedef float  f32x4 __attribute__((ext_vector_type(4)));

#define WN0 (2048*64)     // W_ih0 elems
#define WN1 (2048*512)    // W_hh0 / W_ih1 / W_hh1 elems
#define WTOT (WN0 + 3*WN1)

__device__ __forceinline__ float sigf(float x){ return 1.0f/(1.0f+expf(-x)); }

// Reduce 4 values across a 256-thread block. red must be float[16] shared.
__device__ __forceinline__ void block_reduce4(float&a,float&b,float&c,float&d,float* red){
  #pragma unroll
  for(int o=32;o;o>>=1){
    a+=__shfl_down(a,o); b+=__shfl_down(b,o);
    c+=__shfl_down(c,o); d+=__shfl_down(d,o);
  }
  const int lane = threadIdx.x & 63, wid = threadIdx.x>>6;
  if(lane==0){ red[wid*4+0]=a; red[wid*4+1]=b; red[wid*4+2]=c; red[wid*4+3]=d; }
  __syncthreads();
  a = red[0]+red[4]+red[8]+red[12];
  b = red[1]+red[5]+red[9]+red[13];
  c = red[2]+red[6]+red[10]+red[14];
  d = red[3]+red[7]+red[11]+red[15];
  __syncthreads();
}

// Per-batch-row stats for ln1 (joint LayerNorm over (S,D) = 12800 elems)
__global__ __launch_bounds__(256) void ln1_stats(const float* __restrict__ x,
                                                 float* __restrict__ mu,
                                                 float* __restrict__ rs){
  const int b = blockIdx.x;
  const float* xb = x + (size_t)b*SEQ*DIN;
  float s=0, ss=0, d=0, e=0;
  for (int i=threadIdx.x; i<SEQ*DIN; i+=256){ float v=xb[i]; s+=v; ss+=v*v; }
  __shared__ float red[16];
  block_reduce4(s,ss,d,e,red);
  if (threadIdx.x==0){
    float m = s*(1.0f/(SEQ*DIN));
    mu[b] = m;
    rs[b] = rsqrtf(ss*(1.0f/(SEQ*DIN)) - m*m + EPS);
  }
}

// Split the 4 weight matrices (fp32, (N,K) row-major) into fp16 hi/lo, concat layout.
__global__ __launch_bounds__(256) void wsplit(
    const float* __restrict__ W0, const float* __restrict__ W1,
    const float* __restrict__ W2, const float* __restrict__ W3,
    half_t* __restrict__ Wh, half_t* __restrict__ Wl)
{
  int i = blockIdx.x*256 + threadIdx.x;
  if (i >= WTOT) return;
  const float* src; int off;
  if      (i < WN0)        { src=W0; off=i; }
  else if (i < WN0+WN1)    { src=W1; off=i-WN0; }
  else if (i < WN0+2*WN1)  { src=W2; off=i-WN0-WN1; }
  else                     { src=W3; off=i-WN0-2*WN1; }
  float v = src[off];
  half_t h = (half_t)v;
  Wh[i] = h;
  Wl[i] = (half_t)(v - (float)h);
}

// One tick: 4 gate pre-activation GEMMs via split-fp16 MFMA (3-product), layer-1 skewed.
//  which 0: G_ih0 = ln1(x[:,t,:]) @ W_ih0^T + b_ih0  (K=64, A built in-register)
//  which 1: G_hh0 = h0 @ W_hh0^T + b_hh0             (K=512)
//  which 2: G_ih1 = h0 @ W_ih1^T + b_ih1             (K=512)
//  which 3: G_hh1 = h1 @ W_hh1^T + b_hh1             (K=512)
// grid = (16 n-blks, 8 m-blks, 4 which), block = 256 (4 waves, 2x2), wave tile 32x64
__global__ __launch_bounds__(256) void tick_mm16(
    const float* __restrict__ x, const float* __restrict__ g1, const float* __restrict__ b1,
    const float* __restrict__ mu, const float* __restrict__ rsg,
    const half_t* __restrict__ h0h, const half_t* __restrict__ h0l,
    const half_t* __restrict__ h1h, const half_t* __restrict__ h1l,
    const half_t* __restrict__ Wh, const half_t* __restrict__ Wl,
    const float* __restrict__ b_ih0, const float* __restrict__ b_hh0,
    const float* __restrict__ b_ih1, const float* __restrict__ b_hh1,
    float* __restrict__ G, int t)
{
  const int which = blockIdx.z;
  const int tid  = threadIdx.x;
  const int lane = tid & 63;
  const int w    = tid >> 6;
  const int lrow = lane & 15;          // row within a 16-tile (A: m, B: n, D: col)
  const int lk   = (lane >> 4) * 8;    // k offset within the 32-chunk

  const int wm0 = blockIdx.y*64 + (w>>1)*32;   // wave m origin (32 rows)
  const int wn0 = blockIdx.x*128 + (w&1)*64;   // wave n origin (64 cols)

  const half_t* Ah = h0h; const half_t* Al = h0l;
  const half_t* Bh = Wh + WN0; const half_t* Bl = Wl + WN0;
  const float* bias = b_hh0;
  int Kd = HID;
  if (which==0){ Bh=Wh; Bl=Wl; bias=b_ih0; Kd=DIN; }
  else if (which==2){ Bh=Wh+WN0+WN1; Bl=Wl+WN0+WN1; bias=b_ih1; }
  else if (which==3){ Ah=h1h; Al=h1l; Bh=Wh+WN0+2*WN1; Bl=Wl+WN0+2*WN1; bias=b_hh1; }

  const int tq = (t < SEQ) ? t : (SEQ-1);   // t==200 layer0 result unused

  f32x4 acc[2][4];
  #pragma unroll
  for (int mi=0;mi<2;mi++)
    #pragma unroll
    for (int ni=0;ni<4;ni++)
      acc[mi][ni] = (f32x4){0.f,0.f,0.f,0.f};

  for (int k0 = 0; k0 < Kd; k0 += 32) {
    half8 a_h[2], a_l[2], b_hv[4], b_lv[4];
    #pragma unroll
    for (int ni=0;ni<4;ni++){
      const size_t boff = (size_t)(wn0+ni*16+lrow)*Kd + k0 + lk;
      b_hv[ni] = *(const half8*)(Bh + boff);
      b_lv[ni] = *(const half8*)(Bl + boff);
    }
    #pragma unroll
    for (int mi=0;mi<2;mi++){
      if (which == 0) {
        const int b = wm0 + mi*16 + lrow;
        const float m_ = mu[b], r_ = rsg[b];
        const float* xp = x  + (size_t)b*(SEQ*DIN) + (size_t)tq*DIN + k0 + lk;
        const float* gp = g1 + (size_t)tq*DIN + k0 + lk;
        const float* bp = b1 + (size_t)tq*DIN + k0 + lk;
        #pragma unroll
        for (int j=0;j<8;j++){
          float v = (xp[j]-m_)*r_*gp[j] + bp[j];
          half_t hv = (half_t)v;
          a_h[mi][j] = hv;
          a_l[mi][j] = (half_t)(v - (float)hv);
        }
      } else {
        const size_t aoff = (size_t)(wm0+mi*16+lrow)*Kd + k0 + lk;
        a_h[mi] = *(const half8*)(Ah + aoff);
        a_l[mi] = *(const half8*)(Al + aoff);
      }
    }
    #pragma unroll
    for (int mi=0;mi<2;mi++)
      #pragma unroll
      for (int ni=0;ni<4;ni++){
        acc[mi][ni] = __builtin_amdgcn_mfma_f32_16x16x32_f16(a_h[mi], b_hv[ni], acc[mi][ni], 0,0,0);
        acc[mi][ni] = __builtin_amdgcn_mfma_f32_16x16x32_f16(a_l[mi], b_hv[ni], acc[mi][ni], 0,0,0);
        acc[mi][ni] = __builtin_amdgcn_mfma_f32_16x16x32_f16(a_h[mi], b_lv[ni], acc[mi][ni], 0,0,0);
      }
  }

  // C/D layout: col = lane&15, row = (lane>>4)*4 + r  (dtype-independent, m89-verified)
  float* Gout = G + (size_t)which*BATCH*GW;
  #pragma unroll
  for (int mi=0;mi<2;mi++){
    const int mb = wm0 + mi*16 + (lane>>4)*4;
    #pragma unroll
    for (int ni=0;ni<4;ni++){
      const int n = wn0 + ni*16 + lrow;
      const float bn = bias[n];
      #pragma unroll
      for (int r=0;r<4;r++)
        Gout[(size_t)(mb+r)*GW + n] = acc[mi][ni][r] + bn;
    }
  }
}

// One block per (layer, batch-row): gate LN + cell update + h LN. G staged in LDS.
__global__ __launch_bounds__(256) void tick_update(
    const float* __restrict__ G,
    const float* __restrict__ g_ih0, const float* __restrict__ be_ih0,
    const float* __restrict__ g_hh0, const float* __restrict__ be_hh0,
    const float* __restrict__ g_ho0, const float* __restrict__ be_ho0,
    const float* __restrict__ g_ih1, const float* __restrict__ be_ih1,
    const float* __restrict__ g_hh1, const float* __restrict__ be_hh1,
    const float* __restrict__ g_ho1, const float* __restrict__ be_ho1,
    float* __restrict__ h0, float* __restrict__ c0,
    float* __restrict__ h1, float* __restrict__ c1,
    half_t* __restrict__ h0h, half_t* __restrict__ h0l,
    half_t* __restrict__ h1h, half_t* __restrict__ h1l, int t)
{
  const int layer = blockIdx.x >> 9;
  const int b = blockIdx.x & 511;
  if (layer==0 && t>=SEQ) return;   // layer0 active ticks 0..199
  if (layer==1 && t==0)   return;   // layer1 active ticks 1..200 (processes step t-1)

  const float *Ga,*Gb,*gA,*bA,*gB,*bB,*gH,*bH; float *cs,*hs; half_t *hhx,*hlx;
  if (layer==0){
    Ga = G + (size_t)b*GW;
    Gb = G + (size_t)BATCH*GW + (size_t)b*GW;
    gA=g_ih0; bA=be_ih0; gB=g_hh0; bB=be_hh0; gH=g_ho0; bH=be_ho0;
    cs = c0 + b*HID; hs = h0 + b*HID; hhx = h0h + b*HID; hlx = h0l + b*HID;
  } else {
    Ga = G + 2*(size_t)BATCH*GW + (size_t)b*GW;
    Gb = G + 3*(size_t)BATCH*GW + (size_t)b*GW;
    gA=g_ih1; bA=be_ih1; gB=g_hh1; bB=be_hh1; gH=g_ho1; bH=be_ho1;
    cs = c1 + b*HID; hs = h1 + b*HID; hhx = h1h + b*HID; hlx = h1l + b*HID;
  }

  const int tid = threadIdx.x;
  __shared__ float red[16];
  __shared__ float GS[2*GW];     // 16 KB: Ga then Gb
  __shared__ float su[HID];
  __shared__ float so[HID];

  // Pass 1: stage G into LDS + LN stats for both gate pre-activation vectors
  float sa=0, ssa=0, sb=0, ssb=0;
  for (int i=tid;i<GW;i+=256){
    float va=Ga[i]; GS[i]=va;    sa+=va; ssa+=va*va;
    float vb=Gb[i]; GS[GW+i]=vb; sb+=vb; ssb+=vb*vb;
  }
  block_reduce4(sa,ssa,sb,ssb,red);   // internal __syncthreads covers GS visibility
  const float ma = sa*(1.0f/GW);
  const float ra = rsqrtf(ssa*(1.0f/GW) - ma*ma + EPS);
  const float mb = sb*(1.0f/GW);
  const float rb = rsqrtf(ssb*(1.0f/GW) - mb*mb + EPS);

  // Pass 2: gates (i,f,g,o split), cell update, tanh(c) stats
  float s_u=0, s_uu=0;
  for (int j=tid;j<HID;j+=256){
    float iv = ((GS[j      ]-ma)*ra*gA[j      ]+bA[j      ]) + ((GS[GW+j      ]-mb)*rb*gB[j      ]+bB[j      ]);
    float fv = ((GS[j+  HID]-ma)*ra*gA[j+  HID]+bA[j+  HID]) + ((GS[GW+j+  HID]-mb)*rb*gB[j+  HID]+bB[j+  HID]);
    float gv = ((GS[j+2*HID]-ma)*ra*gA[j+2*HID]+bA[j+2*HID]) + ((GS[GW+j+2*HID]-mb)*rb*gB[j+2*HID]+bB[j+2*HID]);
    float ov = ((GS[j+3*HID]-ma)*ra*gA[j+3*HID]+bA[j+3*HID]) + ((GS[GW+j+3*HID]-mb)*rb*gB[j+3*HID]+bB[j+3*HID]);
    float cn = sigf(fv)*cs[j] + sigf(iv)*tanhf(gv);
    cs[j] = cn;
    float u = tanhf(cn);
    su[j] = u; so[j] = sigf(ov);
    s_u += u; s_uu += u*u;
  }
  float d3=0,d4=0;
  block_reduce4(s_u,s_uu,d3,d4,red);
  const float mu_u = s_u*(1.0f/HID);
  const float ru   = rsqrtf(s_uu*(1.0f/HID) - mu_u*mu_u + EPS);

  // Pass 3: h = sigmoid(o) * LN(tanh(c)); emit fp32 + fp16 hi/lo split
  for (int j=tid;j<HID;j+=256){
    float v = so[j] * ((su[j]-mu_u)*ru*gH[j] + bH[j]);
    hs[j] = v;
    half_t hv = (half_t)v;
    hhx[j] = hv;
    hlx[j] = (half_t)(v - (float)hv);
  }
}

// Dense head: 512 -> 128 -> 64 -> 32 -> 1, one block per batch row
__global__ __launch_bounds__(256) void head_kernel(
    const float* __restrict__ h1,
    const float* __restrict__ Wd1, const float* __restrict__ bd1,
    const float* __restrict__ Wd2, const float* __restrict__ bd2,
    const float* __restrict__ Wd3, const float* __restrict__ bd3,
    const float* __restrict__ Wd4, const float* __restrict__ bd4,
    float* __restrict__ out)
{
  const int b = blockIdx.x;
  __shared__ float hv[HID];
  __shared__ float z1[128];
  __shared__ float z2[64];
  __shared__ float z3[32];
  const int tid = threadIdx.x;
  for (int i=tid;i<HID;i+=256) hv[i]=h1[(size_t)b*HID+i];
  __syncthreads();
  if (tid<128){
    float acc=bd1[tid]; const float* w=Wd1+(size_t)tid*512;
    for(int k=0;k<512;k++) acc+=hv[k]*w[k];
    z1[tid]=fmaxf(acc,0.f);
  }
  __syncthreads();
  if (tid<64){
    float acc=bd2[tid]; const float* w=Wd2+(size_t)tid*128;
    for(int k=0;k<128;k++) acc+=z1[k]*w[k];
    z2[tid]=fmaxf(acc,0.f);
  }
  __syncthreads();
  if (tid<32){
    float acc=bd3[tid]; const float* w=Wd3+(size_t)tid*64;
    for(int k=0;k<64;k++) acc+=z2[k]*w[k];
    z3[tid]=fmaxf(acc,0.f);
  }
  __syncthreads();
  if (tid==0){
    float acc=bd4[0];
    for(int k=0;k<32;k++) acc+=z3[k]*Wd4[k];
    out[b]=acc;
  }
}

extern "C" void kernel_launch(void* const* d_in, const int* in_sizes, int n_in,
                              void* d_out, int out_size, void* d_ws, size_t ws_size,
                              hipStream_t stream) {
  const float* x      = (const float*)d_in[0];
  const float* ln1_g  = (const float*)d_in[1];
  const float* ln1_b  = (const float*)d_in[2];
  const float* W_ih0  = (const float*)d_in[3];
  const float* b_ih0  = (const float*)d_in[4];
  const float* W_hh0  = (const float*)d_in[5];
  const float* b_hh0  = (const float*)d_in[6];
  const float* g_ih0  = (const float*)d_in[7];
  const float* be_ih0 = (const float*)d_in[8];
  const float* g_hh0  = (const float*)d_in[9];
  const float* be_hh0 = (const float*)d_in[10];
  const float* g_ho0  = (const float*)d_in[11];
  const float* be_ho0 = (const float*)d_in[12];
  const float* W_ih1  = (const float*)d_in[13];
  const float* b_ih1  = (const float*)d_in[14];
  const float* W_hh1  = (const float*)d_in[15];
  const float* b_hh1  = (const float*)d_in[16];
  const float* g_ih1  = (const float*)d_in[17];
  const float* be_ih1 = (const float*)d_in[18];
  const float* g_hh1  = (const float*)d_in[19];
  const float* be_hh1 = (const float*)d_in[20];
  const float* g_ho1  = (const float*)d_in[21];
  const float* be_ho1 = (const float*)d_in[22];
  const float* Wd1    = (const float*)d_in[23];
  const float* bd1    = (const float*)d_in[24];
  const float* Wd2    = (const float*)d_in[25];
  const float* bd2    = (const float*)d_in[26];
  const float* Wd3    = (const float*)d_in[27];
  const float* bd3    = (const float*)d_in[28];
  const float* Wd4    = (const float*)d_in[29];
  const float* bd4    = (const float*)d_in[30];
  float* out = (float*)d_out;

  // ---- workspace layout ----
  float* ws = (float*)d_ws;
  float* G  = ws;                                   // 4*512*2048 floats = 16 MB
  float* h0 = G  + 4*(size_t)BATCH*GW;              // fp32 state block (zeroed)
  float* c0 = h0 + (size_t)BATCH*HID;
  float* h1 = c0 + (size_t)BATCH*HID;
  float* c1 = h1 + (size_t)BATCH*HID;
  half_t* h0h = (half_t*)(c1 + (size_t)BATCH*HID);  // fp16 state splits (zeroed)
  half_t* h0l = h0h + (size_t)BATCH*HID;
  half_t* h1h = h0l + (size_t)BATCH*HID;
  half_t* h1l = h1h + (size_t)BATCH*HID;
  float* mu = (float*)(h1l + (size_t)BATCH*HID);    // 512
  float* rs = mu + BATCH;                           // 512
  half_t* Wh = (half_t*)(rs + BATCH);               // WTOT halves
  half_t* Wl = Wh + (size_t)WTOT;                   // WTOT halves

  // zero h0,c0,h1,c1 (fp32) + h0h,h0l,h1h,h1l (fp16) in one contiguous memset
  hipMemsetAsync(h0, 0, 4*(size_t)BATCH*HID*4 + 4*(size_t)BATCH*HID*2, stream);

  ln1_stats<<<BATCH, 256, 0, stream>>>(x, mu, rs);
  wsplit<<<(WTOT+255)/256, 256, 0, stream>>>(W_ih0, W_hh0, W_ih1, W_hh1, Wh, Wl);

  dim3 mgrid(16, 8, 4);
  for (int t = 0; t <= SEQ; ++t) {
    tick_mm16<<<mgrid, 256, 0, stream>>>(x, ln1_g, ln1_b, mu, rs,
        h0h, h0l, h1h, h1l, Wh, Wl,
        b_ih0, b_hh0, b_ih1, b_hh1, G, t);
    tick_update<<<dim3(1024), 256, 0, stream>>>(G,
        g_ih0, be_ih0, g_hh0, be_hh0, g_ho0, be_ho0,
        g_ih1, be_ih1, g_hh1, be_hh1, g_ho1, be_ho1,
        h0, c0, h1, c1, h0h, h0l, h1h, h1l, t);
  }
  head_kernel<<<BATCH, 256, 0, stream>>>(h1, Wd1, bd1, Wd2, bd2, Wd3, bd3, Wd4, bd4, out);
}